// Round 5
// baseline (254.930 us; speedup 1.0000x reference)
//
#include <hip/hip_runtime.h>
#include <stdint.h>

#define CC 22
#define START_I 20
#define STOP_I 21
#define BB 64
#define LL 512
#define DD 512
#define NEGV -100000.0f
#define NCH 32
#define CS 16
#define WPB 16  // waves (batches) per k_pfx block: 4 waves/SIMD for latency hiding

// ws layout
#define EMIT_FLOATS ((BB * LL + CS) * CC)                // + CS rows slack
#define BP_OFF (((EMIT_FLOATS * 4) + 255) & ~255)
#define BP_BYTES (BB * LL * CC)
#define META_OFF ((BP_OFF + BP_BYTES + 255) & ~255)
#define PV_OFF (META_OFF + 1024)                         // 64*32*22 floats

// ---------------- emissions GEMM: emit[row][c] = x[row]·W[c] + b[c] ----------------
// 2 classes per thread: thread = (row, cpair); 11 threads share one x row.
__global__ __launch_bounds__(256) void k_emit(const float* __restrict__ x,
                                              const float* __restrict__ W,
                                              const float* __restrict__ bias,
                                              float* __restrict__ emit) {
  __shared__ float Wl[CC * 516];  // row-major, stride 516 (16B aligned, bank-spread)
  int tid = threadIdx.x;
  for (int g = tid; g < CC * DD; g += 256) {
    int c = g >> 9;
    int d = g & (DD - 1);
    Wl[c * 516 + d] = W[g];
  }
  __syncthreads();
  int gtid = blockIdx.x * 256 + tid;  // 1408*256 = 360448 = 11 * 32768 exactly
  int c = gtid % 11;
  int row = gtid / 11;                // [0, 32768)
  float b0 = bias[c];
  float b1 = bias[c + 11];
  const float4* xr = (const float4*)(x + (size_t)row * DD);
  const float* w0 = Wl + c * 516;
  const float* w1 = Wl + (c + 11) * 516;
  float acc0 = 0.f, acc1 = 0.f;
#pragma unroll 4
  for (int i = 0; i < DD / 4; ++i) {
    float4 a = xr[i];
    float4 u = *(const float4*)(w0 + 4 * i);
    float4 v = *(const float4*)(w1 + 4 * i);
    acc0 += a.x * u.x + a.y * u.y + a.z * u.z + a.w * u.w;
    acc1 += a.x * v.x + a.y * v.y + a.z * v.z + a.w * v.w;
  }
  emit[(size_t)row * CC + c] = acc0 + b0;
  emit[(size_t)row * CC + c + 11] = acc1 + b1;
}

__device__ __forceinline__ float rlf(float v, int l) {
  return __int_as_float(__builtin_amdgcn_readlane(__float_as_int(v), l));
}
__device__ __forceinline__ float bperm_f(int addr, float v) {
  return __int_as_float(__builtin_amdgcn_ds_bpermute(addr, __float_as_int(v)));
}

// cross-half max via v_permlane32_swap (VALU-speed lane^32 exchange, gfx950)
__device__ __forceinline__ float xteam_max(float mh) {
#if __has_builtin(__builtin_amdgcn_permlane32_swap)
  typedef unsigned v2u __attribute__((ext_vector_type(2)));
  v2u r = __builtin_amdgcn_permlane32_swap(__float_as_uint(mh), __float_as_uint(mh),
                                           false, false);
  return fmaxf(__uint_as_float(r.x), __uint_as_float(r.y));
#else
  float a = mh, b2 = mh;
  asm volatile("v_permlane32_swap_b32 %0, %1" : "+v"(a), "+v"(b2));
  return fmaxf(a, b2);
#endif
}

// One exact Viterbi step, 2-team layout (h = lane>>5 owns frm 11h..11h+10):
// 11 bpermute gathers + 11 adds + max tree + permlane cross-team max.
// fmax is exactly associative -> bit-identical to the reference reduction.
#define VSTEP2(EV)                                                   \
  {                                                                  \
    float g0 = bperm_f(ab + 0, st), g1 = bperm_f(ab + 4, st);        \
    float g2 = bperm_f(ab + 8, st), g3 = bperm_f(ab + 12, st);       \
    float g4 = bperm_f(ab + 16, st), g5 = bperm_f(ab + 20, st);      \
    float g6 = bperm_f(ab + 24, st), g7 = bperm_f(ab + 28, st);      \
    float g8 = bperm_f(ab + 32, st), g9 = bperm_f(ab + 36, st);      \
    float g10 = bperm_f(ab + 40, st);                                \
    float d0 = g0 + Tw[0], d1 = g1 + Tw[1], d2 = g2 + Tw[2];         \
    float d3 = g3 + Tw[3], d4 = g4 + Tw[4], d5 = g5 + Tw[5];         \
    float d6 = g6 + Tw[6], d7 = g7 + Tw[7], d8 = g8 + Tw[8];         \
    float d9 = g9 + Tw[9], d10 = g10 + Tw[10];                       \
    float m0 = fmaxf(fmaxf(d0, d1), d2);                             \
    float m1 = fmaxf(fmaxf(d3, d4), d5);                             \
    float m2 = fmaxf(fmaxf(d6, d7), d8);                             \
    float m3 = fmaxf(d9, d10);                                       \
    float mh = fmaxf(fmaxf(fmaxf(m0, m1), m2), m3);                  \
    st = xteam_max(mh) + (EV);                                       \
  }

// ---------------- prefix pass: 16 independent batch-waves per block ----------
__global__ __launch_bounds__(1024) void k_pfx(const float* __restrict__ emit,
                                              const float* __restrict__ mask,
                                              const float* __restrict__ trans,
                                              float* __restrict__ out_score,
                                              float* __restrict__ pv,
                                              int* __restrict__ meta) {
  const int b = blockIdx.x * WPB + (threadIdx.x >> 6);  // one batch per wave
  const int lane = threadIdx.x & 63;
  const int h = lane >> 5;       // team: which frm half
  const int p = lane & 31;       // to-state (valid < CC)
  const int toc = p < CC ? p : CC - 1;

  float Tw[11];  // trans[to=p][frm=11h+j]
#pragma unroll
  for (int j = 0; j < 11; ++j) Tw[j] = trans[toc * CC + 11 * h + j];
  const float Tstop = trans[STOP_I * CC + toc];
  const int ab = 44 * h;  // bpermute byte base: gathers st from lanes 11h+j

  int n = 0;
#pragma unroll
  for (int k = 0; k < 8; ++k) {
    unsigned long long bl = __ballot(mask[b * LL + k * 64 + lane] > 0.0f);
    n += __popcll(bl);
  }

  const float* eb = emit + (size_t)b * LL * CC;
  float st = (p == START_I) ? 0.0f : NEGV;

  float ebuf[CS];
#pragma unroll
  for (int q = 0; q < CS; ++q) {
    ebuf[q] = eb[q * CC + toc];
    asm volatile("" : "+v"(ebuf[q]));  // cold-start materialize (once)
  }

  float* pvb = pv + (size_t)b * NCH * CC;
  const int cfull = n >> 4;
  for (int c = 0; c < cfull; ++c) {
    if (lane < CC) pvb[c * CC + lane] = st;  // state BEFORE chunk c (off-chain)
    float en[CS];
#pragma unroll
    for (int q = 0; q < CS; ++q) en[q] = eb[((c + 1) * CS + q) * CC + toc];
    VSTEP2(ebuf[0])  VSTEP2(ebuf[1])  VSTEP2(ebuf[2])  VSTEP2(ebuf[3])
    VSTEP2(ebuf[4])  VSTEP2(ebuf[5])  VSTEP2(ebuf[6])  VSTEP2(ebuf[7])
    VSTEP2(ebuf[8])  VSTEP2(ebuf[9])  VSTEP2(ebuf[10]) VSTEP2(ebuf[11])
    VSTEP2(ebuf[12]) VSTEP2(ebuf[13]) VSTEP2(ebuf[14]) VSTEP2(ebuf[15])
#pragma unroll
    for (int q = 0; q < CS; ++q) {
      asm volatile("" : "+v"(en[q]));
      ebuf[q] = en[q];
    }
  }
  const int rem = n & (CS - 1);
  if (rem) {
    if (lane < CC) pvb[cfull * CC + lane] = st;
#pragma unroll
    for (int q = 0; q < CS; ++q) {
      if (q < rem) VSTEP2(ebuf[q]);  // wave-uniform branch
    }
  }

  float fin = st + Tstop;
  if (lane < CC) out_score[b * CC + lane] = fin;

  // best tag: uniform readlane sweep (strict > keeps first index on ties)
  float bv = -3.0e38f;
  int bt = 0;
#pragma unroll
  for (int k = 0; k < CC; ++k) {
    float v = rlf(fin, k);
    bool g = v > bv;
    bv = g ? v : bv;
    bt = g ? k : bt;
  }
  if (lane == 0) { meta[b] = n; meta[BB + b] = bt; }
}

// ---------------- parallel replay: backpointers from exact checkpoints ----------------
__global__ __launch_bounds__(64) void k_rep(const float* __restrict__ emit,
                                            const float* __restrict__ trans,
                                            const float* __restrict__ pv,
                                            const int* __restrict__ meta,
                                            unsigned char* __restrict__ bp) {
  const int c = blockIdx.x, b = blockIdx.y;
  const int lane = threadIdx.x;
  const int n = meta[b];
  const int t0 = c * CS;
  if (t0 >= n) return;
  const int lc = lane < CC ? lane : CC - 1;
  float Trow[CC];
#pragma unroll
  for (int j = 0; j < CC; ++j) Trow[j] = trans[lc * CC + j];
  float st = pv[((size_t)b * NCH + c) * CC + lc];
  const float* eb = emit + (size_t)b * LL * CC;
  float ev[CS];
#pragma unroll
  for (int q = 0; q < CS; ++q) {
    ev[q] = eb[(t0 + q) * CC + lc];
    asm volatile("" : "+v"(ev[q]));
  }
  unsigned char* bpb = bp + (size_t)b * LL * CC;
  const int m = (n - t0) < CS ? (n - t0) : CS;
#pragma unroll
  for (int q = 0; q < CS; ++q) {
    if (q < m) {
      float cand[CC];
#pragma unroll
      for (int j = 0; j < CC; ++j) cand[j] = rlf(st, j) + Trow[j];
      float m0 = fmaxf(fmaxf(cand[0], cand[1]), cand[2]);
      float m1 = fmaxf(fmaxf(cand[3], cand[4]), cand[5]);
      float m2 = fmaxf(fmaxf(cand[6], cand[7]), cand[8]);
      float m3 = fmaxf(fmaxf(cand[9], cand[10]), cand[11]);
      float m4 = fmaxf(fmaxf(cand[12], cand[13]), cand[14]);
      float m5 = fmaxf(fmaxf(cand[15], cand[16]), cand[17]);
      float m6 = fmaxf(fmaxf(cand[18], cand[19]), cand[20]);
      float n0 = fmaxf(fmaxf(m0, m1), m2);
      float n1 = fmaxf(fmaxf(m3, m4), m5);
      float n2 = fmaxf(m6, cand[21]);
      float mx = fmaxf(fmaxf(n0, n1), n2);
      // first-index argmax over frm (matches jnp.argmax tie-break)
      unsigned u = 0;
#pragma unroll
      for (int j = 0; j < CC; ++j) u |= (cand[j] == mx) ? (1u << j) : 0u;
      int bpi = __builtin_ctz(u);
      if (lane < CC) bpb[(t0 + q) * CC + lane] = (unsigned char)bpi;
      st = mx + ev[q];
    }
  }
}

// ---------------- backtrace: chunk-composed backpointer maps ----------------
__global__ __launch_bounds__(64) void k_back(const unsigned char* __restrict__ bp,
                                             const int* __restrict__ meta,
                                             float* __restrict__ out_path) {
  __shared__ __align__(16) unsigned char bps[LL * CC];  // 11264 B
  __shared__ unsigned char gs[64 * CC];                 // per-chunk composed maps
  const int b = blockIdx.x, lane = threadIdx.x;
  const int n = meta[b];
  const int bt = meta[BB + b];
  const uint32_t* src = (const uint32_t*)(bp + (size_t)b * LL * CC);
  uint32_t* dst = (uint32_t*)bps;
  for (int i = lane; i < (LL * CC) / 4; i += 64) dst[i] = src[i];
  __syncthreads();
  // lane k composes the 8-step map of chunk k (inactive steps = identity)
  const int k = lane;
  for (int c = 0; c < CC; ++c) {
    int tag = c;
#pragma unroll
    for (int j = 7; j >= 0; --j) {
      int t = 8 * k + j;
      int nv = bps[t * CC + tag];
      tag = (t < n) ? nv : tag;
    }
    gs[k * CC + c] = (unsigned char)tag;
  }
  __syncthreads();
  // 64-step dependent chain over chunk maps (broadcast LDS reads)
  int tag = bt, entry = bt;
  for (int kk = 63; kk >= 0; --kk) {
    if (lane == kk) entry = tag;
    tag = gs[kk * CC + tag];
  }
  // parallel replay within each chunk
  tag = entry;
  float* op = out_path + (size_t)b * LL;
#pragma unroll
  for (int j = 7; j >= 0; --j) {
    int t = 8 * k + j;
    bool act = t < n;
    op[t] = act ? (float)tag : 0.0f;
    int nv = bps[t * CC + tag];
    tag = act ? nv : tag;
  }
}

extern "C" void kernel_launch(void* const* d_in, const int* in_sizes, int n_in,
                              void* d_out, int out_size, void* d_ws, size_t ws_size,
                              hipStream_t stream) {
  const float* x = (const float*)d_in[0];
  const float* mask = (const float*)d_in[1];
  const float* W = (const float*)d_in[2];
  const float* bias = (const float*)d_in[3];
  const float* trans = (const float*)d_in[4];
  float* out_score = (float*)d_out;                 // [B, C] f32
  float* out_path = (float*)d_out + BB * CC;        // [B, L] written as f32 values
  char* ws = (char*)d_ws;
  float* emit = (float*)ws;
  unsigned char* bp = (unsigned char*)(ws + BP_OFF);
  int* meta = (int*)(ws + META_OFF);
  float* pvp = (float*)(ws + PV_OFF);

  k_emit<<<dim3(1408), dim3(256), 0, stream>>>(x, W, bias, emit);
  k_pfx<<<dim3(BB / WPB), dim3(WPB * 64), 0, stream>>>(emit, mask, trans, out_score, pvp, meta);
  k_rep<<<dim3(NCH, BB), dim3(64), 0, stream>>>(emit, trans, pvp, meta, bp);
  k_back<<<dim3(BB), dim3(64), 0, stream>>>(bp, meta, out_path);
}

// Round 6
// 253.903 us; speedup vs baseline: 1.0040x; 1.0040x over previous
//
#include <hip/hip_runtime.h>
#include <stdint.h>

#define CC 22
#define START_I 20
#define STOP_I 21
#define BB 64
#define LL 512
#define DD 512
#define NEGV -100000.0f
#define NCH 32
#define CS 16
#define WPB 16  // waves (batches) per k_pfx block: 4 waves/SIMD for latency hiding

// ws layout
#define EMIT_FLOATS ((BB * LL + CS) * CC)                // + CS rows slack
#define BP_OFF (((EMIT_FLOATS * 4) + 255) & ~255)
#define BP_BYTES (BB * LL * CC)
#define META_OFF ((BP_OFF + BP_BYTES + 255) & ~255)
#define PV_OFF (META_OFF + 1024)                         // 64*32*22 floats

// ---------------- emissions GEMM: emit[row][c] = x[row]·W[c] + b[c] ----------------
// 2 classes per thread: thread = (row, cpair); 11 threads share one x row.
__global__ __launch_bounds__(256) void k_emit(const float* __restrict__ x,
                                              const float* __restrict__ W,
                                              const float* __restrict__ bias,
                                              float* __restrict__ emit) {
  __shared__ float Wl[CC * 516];  // row-major, stride 516 (16B aligned, bank-spread)
  int tid = threadIdx.x;
  for (int g = tid; g < CC * DD; g += 256) {
    int c = g >> 9;
    int d = g & (DD - 1);
    Wl[c * 516 + d] = W[g];
  }
  __syncthreads();
  int gtid = blockIdx.x * 256 + tid;  // 1408*256 = 360448 = 11 * 32768 exactly
  int c = gtid % 11;
  int row = gtid / 11;                // [0, 32768)
  float b0 = bias[c];
  float b1 = bias[c + 11];
  const float4* xr = (const float4*)(x + (size_t)row * DD);
  const float* w0 = Wl + c * 516;
  const float* w1 = Wl + (c + 11) * 516;
  float acc0 = 0.f, acc1 = 0.f;
#pragma unroll 4
  for (int i = 0; i < DD / 4; ++i) {
    float4 a = xr[i];
    float4 u = *(const float4*)(w0 + 4 * i);
    float4 v = *(const float4*)(w1 + 4 * i);
    acc0 += a.x * u.x + a.y * u.y + a.z * u.z + a.w * u.w;
    acc1 += a.x * v.x + a.y * v.y + a.z * v.z + a.w * v.w;
  }
  emit[(size_t)row * CC + c] = acc0 + b0;
  emit[(size_t)row * CC + c + 11] = acc1 + b1;
}

__device__ __forceinline__ float rlf(float v, int l) {
  return __int_as_float(__builtin_amdgcn_readlane(__float_as_int(v), l));
}
__device__ __forceinline__ float bperm_f(int addr, float v) {
  return __int_as_float(__builtin_amdgcn_ds_bpermute(addr, __float_as_int(v)));
}

// cross-half max via v_permlane32_swap (VALU-speed lane^32 exchange, gfx950)
__device__ __forceinline__ float xteam_max(float mh) {
#if __has_builtin(__builtin_amdgcn_permlane32_swap)
  typedef unsigned v2u __attribute__((ext_vector_type(2)));
  v2u r = __builtin_amdgcn_permlane32_swap(__float_as_uint(mh), __float_as_uint(mh),
                                           false, false);
  return fmaxf(__uint_as_float(r.x), __uint_as_float(r.y));
#else
  float a = mh, b2 = mh;
  asm volatile("v_permlane32_swap_b32 %0, %1" : "+v"(a), "+v"(b2));
  return fmaxf(a, b2);
#endif
}

// One exact Viterbi step, 2-team layout (h = lane>>5 owns frm 11h..11h+10):
// 11 bpermute gathers + 11 adds + max tree + permlane cross-team max.
// fmax is exactly associative -> bit-identical to the reference reduction.
#define VSTEP2(EV)                                                   \
  {                                                                  \
    float g0 = bperm_f(ab + 0, st), g1 = bperm_f(ab + 4, st);        \
    float g2 = bperm_f(ab + 8, st), g3 = bperm_f(ab + 12, st);       \
    float g4 = bperm_f(ab + 16, st), g5 = bperm_f(ab + 20, st);      \
    float g6 = bperm_f(ab + 24, st), g7 = bperm_f(ab + 28, st);      \
    float g8 = bperm_f(ab + 32, st), g9 = bperm_f(ab + 36, st);      \
    float g10 = bperm_f(ab + 40, st);                                \
    float d0 = g0 + Tw[0], d1 = g1 + Tw[1], d2 = g2 + Tw[2];         \
    float d3 = g3 + Tw[3], d4 = g4 + Tw[4], d5 = g5 + Tw[5];         \
    float d6 = g6 + Tw[6], d7 = g7 + Tw[7], d8 = g8 + Tw[8];         \
    float d9 = g9 + Tw[9], d10 = g10 + Tw[10];                       \
    float m0 = fmaxf(fmaxf(d0, d1), d2);                             \
    float m1 = fmaxf(fmaxf(d3, d4), d5);                             \
    float m2 = fmaxf(fmaxf(d6, d7), d8);                             \
    float m3 = fmaxf(d9, d10);                                       \
    float mh = fmaxf(fmaxf(fmaxf(m0, m1), m2), m3);                  \
    st = xteam_max(mh) + (EV);                                       \
  }

// ---------------- prefix pass: 16 independent batch-waves per block --------------
// __launch_bounds__(1024, 4): 4 waves/EU -> VGPR cap 128 (round-5's implicit cap
// of 32 spilled the prefetch to scratch). 8-deep prefetch, checkpoint every 16.
__global__ __launch_bounds__(1024, 4) void k_pfx(const float* __restrict__ emit,
                                                 const float* __restrict__ mask,
                                                 const float* __restrict__ trans,
                                                 float* __restrict__ out_score,
                                                 float* __restrict__ pv,
                                                 int* __restrict__ meta) {
  const int b = blockIdx.x * WPB + (threadIdx.x >> 6);  // one batch per wave
  const int lane = threadIdx.x & 63;
  const int h = lane >> 5;       // team: which frm half
  const int p = lane & 31;       // to-state (valid < CC)
  const int toc = p < CC ? p : CC - 1;

  float Tw[11];  // trans[to=p][frm=11h+j]
#pragma unroll
  for (int j = 0; j < 11; ++j) Tw[j] = trans[toc * CC + 11 * h + j];
  const float Tstop = trans[STOP_I * CC + toc];
  const int ab = 44 * h;  // bpermute byte base: gathers st from lanes 11h+j

  int n = 0;
#pragma unroll
  for (int k = 0; k < 8; ++k) {
    unsigned long long bl = __ballot(mask[b * LL + k * 64 + lane] > 0.0f);
    n += __popcll(bl);
  }

  const float* eb = emit + (size_t)b * LL * CC;
  float st = (p == START_I) ? 0.0f : NEGV;

  float ebuf[8];
#pragma unroll
  for (int q = 0; q < 8; ++q) {
    ebuf[q] = eb[q * CC + toc];
    asm volatile("" : "+v"(ebuf[q]));  // cold-start materialize (once)
  }

  float* pvb = pv + (size_t)b * NCH * CC;
  const int ofull = n >> 3;  // full 8-step octs
  for (int o = 0; o < ofull; ++o) {
    if (((o & 1) == 0) && lane < CC) pvb[(o >> 1) * CC + lane] = st;  // chunk ckpt
    float en[8];
#pragma unroll
    for (int q = 0; q < 8; ++q) en[q] = eb[((o + 1) * 8 + q) * CC + toc];
    VSTEP2(ebuf[0])  VSTEP2(ebuf[1])  VSTEP2(ebuf[2])  VSTEP2(ebuf[3])
    VSTEP2(ebuf[4])  VSTEP2(ebuf[5])  VSTEP2(ebuf[6])  VSTEP2(ebuf[7])
#pragma unroll
    for (int q = 0; q < 8; ++q) {
      asm volatile("" : "+v"(en[q]));  // vmcnt wait lands after compute
      ebuf[q] = en[q];
    }
  }
  const int rem = n & 7;
  if (rem) {
    if (((ofull & 1) == 0) && lane < CC) pvb[(ofull >> 1) * CC + lane] = st;
#pragma unroll
    for (int q = 0; q < 8; ++q) {
      if (q < rem) VSTEP2(ebuf[q]);  // wave-uniform branch
    }
  }

  float fin = st + Tstop;
  if (lane < CC) out_score[b * CC + lane] = fin;

  // best tag: uniform readlane sweep (strict > keeps first index on ties)
  float bv = -3.0e38f;
  int bt = 0;
#pragma unroll
  for (int k = 0; k < CC; ++k) {
    float v = rlf(fin, k);
    bool g = v > bv;
    bv = g ? v : bv;
    bt = g ? k : bt;
  }
  if (lane == 0) { meta[b] = n; meta[BB + b] = bt; }
}

// ---------------- parallel replay: backpointers from exact checkpoints ----------------
__global__ __launch_bounds__(64) void k_rep(const float* __restrict__ emit,
                                            const float* __restrict__ trans,
                                            const float* __restrict__ pv,
                                            const int* __restrict__ meta,
                                            unsigned char* __restrict__ bp) {
  const int c = blockIdx.x, b = blockIdx.y;
  const int lane = threadIdx.x;
  const int n = meta[b];
  const int t0 = c * CS;
  if (t0 >= n) return;
  const int lc = lane < CC ? lane : CC - 1;
  float Trow[CC];
#pragma unroll
  for (int j = 0; j < CC; ++j) Trow[j] = trans[lc * CC + j];
  float st = pv[((size_t)b * NCH + c) * CC + lc];
  const float* eb = emit + (size_t)b * LL * CC;
  float ev[CS];
#pragma unroll
  for (int q = 0; q < CS; ++q) {
    ev[q] = eb[(t0 + q) * CC + lc];
    asm volatile("" : "+v"(ev[q]));
  }
  unsigned char* bpb = bp + (size_t)b * LL * CC;
  const int m = (n - t0) < CS ? (n - t0) : CS;
#pragma unroll
  for (int q = 0; q < CS; ++q) {
    if (q < m) {
      float cand[CC];
#pragma unroll
      for (int j = 0; j < CC; ++j) cand[j] = rlf(st, j) + Trow[j];
      float m0 = fmaxf(fmaxf(cand[0], cand[1]), cand[2]);
      float m1 = fmaxf(fmaxf(cand[3], cand[4]), cand[5]);
      float m2 = fmaxf(fmaxf(cand[6], cand[7]), cand[8]);
      float m3 = fmaxf(fmaxf(cand[9], cand[10]), cand[11]);
      float m4 = fmaxf(fmaxf(cand[12], cand[13]), cand[14]);
      float m5 = fmaxf(fmaxf(cand[15], cand[16]), cand[17]);
      float m6 = fmaxf(fmaxf(cand[18], cand[19]), cand[20]);
      float n0 = fmaxf(fmaxf(m0, m1), m2);
      float n1 = fmaxf(fmaxf(m3, m4), m5);
      float n2 = fmaxf(m6, cand[21]);
      float mx = fmaxf(fmaxf(n0, n1), n2);
      // first-index argmax over frm (matches jnp.argmax tie-break)
      unsigned u = 0;
#pragma unroll
      for (int j = 0; j < CC; ++j) u |= (cand[j] == mx) ? (1u << j) : 0u;
      int bpi = __builtin_ctz(u);
      if (lane < CC) bpb[(t0 + q) * CC + lane] = (unsigned char)bpi;
      st = mx + ev[q];
    }
  }
}

// ---------------- backtrace: chunk-composed backpointer maps ----------------
__global__ __launch_bounds__(64) void k_back(const unsigned char* __restrict__ bp,
                                             const int* __restrict__ meta,
                                             float* __restrict__ out_path) {
  __shared__ __align__(16) unsigned char bps[LL * CC];  // 11264 B
  __shared__ unsigned char gs[64 * CC];                 // per-chunk composed maps
  const int b = blockIdx.x, lane = threadIdx.x;
  const int n = meta[b];
  const int bt = meta[BB + b];
  const uint32_t* src = (const uint32_t*)(bp + (size_t)b * LL * CC);
  uint32_t* dst = (uint32_t*)bps;
  for (int i = lane; i < (LL * CC) / 4; i += 64) dst[i] = src[i];
  __syncthreads();
  // lane k composes the 8-step map of chunk k (inactive steps = identity)
  const int k = lane;
  for (int c = 0; c < CC; ++c) {
    int tag = c;
#pragma unroll
    for (int j = 7; j >= 0; --j) {
      int t = 8 * k + j;
      int nv = bps[t * CC + tag];
      tag = (t < n) ? nv : tag;
    }
    gs[k * CC + c] = (unsigned char)tag;
  }
  __syncthreads();
  // 64-step dependent chain over chunk maps (broadcast LDS reads)
  int tag = bt, entry = bt;
  for (int kk = 63; kk >= 0; --kk) {
    if (lane == kk) entry = tag;
    tag = gs[kk * CC + tag];
  }
  // parallel replay within each chunk
  tag = entry;
  float* op = out_path + (size_t)b * LL;
#pragma unroll
  for (int j = 7; j >= 0; --j) {
    int t = 8 * k + j;
    bool act = t < n;
    op[t] = act ? (float)tag : 0.0f;
    int nv = bps[t * CC + tag];
    tag = act ? nv : tag;
  }
}

extern "C" void kernel_launch(void* const* d_in, const int* in_sizes, int n_in,
                              void* d_out, int out_size, void* d_ws, size_t ws_size,
                              hipStream_t stream) {
  const float* x = (const float*)d_in[0];
  const float* mask = (const float*)d_in[1];
  const float* W = (const float*)d_in[2];
  const float* bias = (const float*)d_in[3];
  const float* trans = (const float*)d_in[4];
  float* out_score = (float*)d_out;                 // [B, C] f32
  float* out_path = (float*)d_out + BB * CC;        // [B, L] written as f32 values
  char* ws = (char*)d_ws;
  float* emit = (float*)ws;
  unsigned char* bp = (unsigned char*)(ws + BP_OFF);
  int* meta = (int*)(ws + META_OFF);
  float* pvp = (float*)(ws + PV_OFF);

  k_emit<<<dim3(1408), dim3(256), 0, stream>>>(x, W, bias, emit);
  k_pfx<<<dim3(BB / WPB), dim3(WPB * 64), 0, stream>>>(emit, mask, trans, out_score, pvp, meta);
  k_rep<<<dim3(NCH, BB), dim3(64), 0, stream>>>(emit, trans, pvp, meta, bp);
  k_back<<<dim3(BB), dim3(64), 0, stream>>>(bp, meta, out_path);
}

// Round 7
// 124.418 us; speedup vs baseline: 2.0490x; 2.0407x over previous
//
#include <hip/hip_runtime.h>
#include <stdint.h>

#define CC 22
#define START_I 20
#define STOP_I 21
#define BB 64
#define LL 512
#define DD 512
#define NEGV -100000.0f
#define NCH 32
#define CS 16

// ws layout
#define EMIT_FLOATS ((BB * LL + CS) * CC)                // + CS rows slack
#define BP_OFF (((EMIT_FLOATS * 4) + 255) & ~255)
#define BP_BYTES (BB * LL * CC)
#define META_OFF ((BP_OFF + BP_BYTES + 255) & ~255)
#define PV_OFF (META_OFF + 1024)                         // 64*32*22 floats

// ---------------- emissions GEMM: emit[row][c] = x[row]·W[c] + b[c] ----------------
// 2 classes per thread: thread = (row, cpair); 11 threads share one x row.
__global__ __launch_bounds__(256) void k_emit(const float* __restrict__ x,
                                              const float* __restrict__ W,
                                              const float* __restrict__ bias,
                                              float* __restrict__ emit) {
  __shared__ float Wl[CC * 516];  // row-major, stride 516 (16B aligned, bank-spread)
  int tid = threadIdx.x;
  for (int g = tid; g < CC * DD; g += 256) {
    int c = g >> 9;
    int d = g & (DD - 1);
    Wl[c * 516 + d] = W[g];
  }
  __syncthreads();
  int gtid = blockIdx.x * 256 + tid;  // 1408*256 = 360448 = 11 * 32768 exactly
  int c = gtid % 11;
  int row = gtid / 11;                // [0, 32768)
  float b0 = bias[c];
  float b1 = bias[c + 11];
  const float4* xr = (const float4*)(x + (size_t)row * DD);
  const float* w0 = Wl + c * 516;
  const float* w1 = Wl + (c + 11) * 516;
  float acc0 = 0.f, acc1 = 0.f;
#pragma unroll 4
  for (int i = 0; i < DD / 4; ++i) {
    float4 a = xr[i];
    float4 u = *(const float4*)(w0 + 4 * i);
    float4 v = *(const float4*)(w1 + 4 * i);
    acc0 += a.x * u.x + a.y * u.y + a.z * u.z + a.w * u.w;
    acc1 += a.x * v.x + a.y * v.y + a.z * v.z + a.w * v.w;
  }
  emit[(size_t)row * CC + c] = acc0 + b0;
  emit[(size_t)row * CC + c + 11] = acc1 + b1;
}

__device__ __forceinline__ float rlf(float v, int l) {
  return __int_as_float(__builtin_amdgcn_readlane(__float_as_int(v), l));
}

// One exact Viterbi step: 22 hazard-free grouped v_readlane (one asm block,
// distinct SGPR dests, no internal reads), then VALU adds (SGPR+VGPR) and a
// v_max3-fusable tree. fmax exactly associative -> bit-identical to reference.
#define VSTEP_RL(EV)                                                         \
  {                                                                          \
    int r0, r1, r2, r3, r4, r5, r6, r7, r8, r9, r10, r11, r12, r13, r14,     \
        r15, r16, r17, r18, r19, r20, r21;                                   \
    asm volatile(                                                            \
        "v_readlane_b32 %[a0], %[vs], 0\n\t"                                 \
        "v_readlane_b32 %[a1], %[vs], 1\n\t"                                 \
        "v_readlane_b32 %[a2], %[vs], 2\n\t"                                 \
        "v_readlane_b32 %[a3], %[vs], 3\n\t"                                 \
        "v_readlane_b32 %[a4], %[vs], 4\n\t"                                 \
        "v_readlane_b32 %[a5], %[vs], 5\n\t"                                 \
        "v_readlane_b32 %[a6], %[vs], 6\n\t"                                 \
        "v_readlane_b32 %[a7], %[vs], 7\n\t"                                 \
        "v_readlane_b32 %[a8], %[vs], 8\n\t"                                 \
        "v_readlane_b32 %[a9], %[vs], 9\n\t"                                 \
        "v_readlane_b32 %[a10], %[vs], 10\n\t"                               \
        "v_readlane_b32 %[a11], %[vs], 11\n\t"                               \
        "v_readlane_b32 %[a12], %[vs], 12\n\t"                               \
        "v_readlane_b32 %[a13], %[vs], 13\n\t"                               \
        "v_readlane_b32 %[a14], %[vs], 14\n\t"                               \
        "v_readlane_b32 %[a15], %[vs], 15\n\t"                               \
        "v_readlane_b32 %[a16], %[vs], 16\n\t"                               \
        "v_readlane_b32 %[a17], %[vs], 17\n\t"                               \
        "v_readlane_b32 %[a18], %[vs], 18\n\t"                               \
        "v_readlane_b32 %[a19], %[vs], 19\n\t"                               \
        "v_readlane_b32 %[a20], %[vs], 20\n\t"                               \
        "v_readlane_b32 %[a21], %[vs], 21\n\t"                               \
        : [a0] "=s"(r0), [a1] "=s"(r1), [a2] "=s"(r2), [a3] "=s"(r3),        \
          [a4] "=s"(r4), [a5] "=s"(r5), [a6] "=s"(r6), [a7] "=s"(r7),        \
          [a8] "=s"(r8), [a9] "=s"(r9), [a10] "=s"(r10), [a11] "=s"(r11),    \
          [a12] "=s"(r12), [a13] "=s"(r13), [a14] "=s"(r14),                 \
          [a15] "=s"(r15), [a16] "=s"(r16), [a17] "=s"(r17),                 \
          [a18] "=s"(r18), [a19] "=s"(r19), [a20] "=s"(r20),                 \
          [a21] "=s"(r21)                                                    \
        : [vs] "v"(st));                                                     \
    float d0 = __int_as_float(r0) + Tw[0];                                   \
    float d1 = __int_as_float(r1) + Tw[1];                                   \
    float d2 = __int_as_float(r2) + Tw[2];                                   \
    float d3 = __int_as_float(r3) + Tw[3];                                   \
    float d4 = __int_as_float(r4) + Tw[4];                                   \
    float d5 = __int_as_float(r5) + Tw[5];                                   \
    float d6 = __int_as_float(r6) + Tw[6];                                   \
    float d7 = __int_as_float(r7) + Tw[7];                                   \
    float d8 = __int_as_float(r8) + Tw[8];                                   \
    float d9 = __int_as_float(r9) + Tw[9];                                   \
    float d10 = __int_as_float(r10) + Tw[10];                                \
    float d11 = __int_as_float(r11) + Tw[11];                                \
    float d12 = __int_as_float(r12) + Tw[12];                                \
    float d13 = __int_as_float(r13) + Tw[13];                                \
    float d14 = __int_as_float(r14) + Tw[14];                                \
    float d15 = __int_as_float(r15) + Tw[15];                                \
    float d16 = __int_as_float(r16) + Tw[16];                                \
    float d17 = __int_as_float(r17) + Tw[17];                                \
    float d18 = __int_as_float(r18) + Tw[18];                                \
    float d19 = __int_as_float(r19) + Tw[19];                                \
    float d20 = __int_as_float(r20) + Tw[20];                                \
    float d21 = __int_as_float(r21) + Tw[21];                                \
    float m0 = fmaxf(fmaxf(d0, d1), d2);                                     \
    float m1 = fmaxf(fmaxf(d3, d4), d5);                                     \
    float m2 = fmaxf(fmaxf(d6, d7), d8);                                     \
    float m3 = fmaxf(fmaxf(d9, d10), d11);                                   \
    float m4 = fmaxf(fmaxf(d12, d13), d14);                                  \
    float m5 = fmaxf(fmaxf(d15, d16), d17);                                  \
    float m6 = fmaxf(fmaxf(d18, d19), d20);                                  \
    float n0 = fmaxf(fmaxf(m0, m1), m2);                                     \
    float n1 = fmaxf(fmaxf(m3, m4), m5);                                     \
    float n2 = fmaxf(m6, d21);                                               \
    float mx = fmaxf(fmaxf(n0, n1), n2);                                     \
    st = mx + (EV);                                                          \
  }

// ---------------- prefix pass: one wave per batch, lane = to-state ----------
__global__ __launch_bounds__(64) void k_pfx(const float* __restrict__ emit,
                                            const float* __restrict__ mask,
                                            const float* __restrict__ trans,
                                            float* __restrict__ out_score,
                                            float* __restrict__ pv,
                                            int* __restrict__ meta) {
  const int b = blockIdx.x;
  const int lane = threadIdx.x;
  const int lc = lane < CC ? lane : CC - 1;

  float Tw[CC];  // trans[to=lane][frm=j], full row per lane
#pragma unroll
  for (int j = 0; j < CC; ++j) Tw[j] = trans[lc * CC + j];
  const float Tstop = trans[STOP_I * CC + lc];

  int n = 0;
#pragma unroll
  for (int k = 0; k < 8; ++k) {
    unsigned long long bl = __ballot(mask[b * LL + k * 64 + lane] > 0.0f);
    n += __popcll(bl);
  }

  const float* eb = emit + (size_t)b * LL * CC;
  float st = (lane == START_I) ? 0.0f : NEGV;

  float ebuf[8];
#pragma unroll
  for (int q = 0; q < 8; ++q) {
    ebuf[q] = eb[q * CC + lc];
    asm volatile("" : "+v"(ebuf[q]));  // cold-start materialize (once)
  }

  float* pvb = pv + (size_t)b * NCH * CC;
  const int ofull = n >> 3;  // full 8-step octs
  for (int o = 0; o < ofull; ++o) {
    if (((o & 1) == 0) && lane < CC) pvb[(o >> 1) * CC + lane] = st;  // ckpt @16
    float en[8];
#pragma unroll
    for (int q = 0; q < 8; ++q) en[q] = eb[((o + 1) * 8 + q) * CC + lc];
    VSTEP_RL(ebuf[0]) VSTEP_RL(ebuf[1]) VSTEP_RL(ebuf[2]) VSTEP_RL(ebuf[3])
    VSTEP_RL(ebuf[4]) VSTEP_RL(ebuf[5]) VSTEP_RL(ebuf[6]) VSTEP_RL(ebuf[7])
#pragma unroll
    for (int q = 0; q < 8; ++q) {
      asm volatile("" : "+v"(en[q]));  // vmcnt wait lands after compute
      ebuf[q] = en[q];
    }
  }
  const int rem = n & 7;
  if (rem) {
    if (((ofull & 1) == 0) && lane < CC) pvb[(ofull >> 1) * CC + lane] = st;
#pragma unroll
    for (int q = 0; q < 8; ++q) {
      if (q < rem) VSTEP_RL(ebuf[q]);  // wave-uniform branch
    }
  }

  float fin = st + Tstop;
  if (lane < CC) out_score[b * CC + lane] = fin;

  // best tag: uniform readlane sweep (strict > keeps first index on ties)
  float bv = -3.0e38f;
  int bt = 0;
#pragma unroll
  for (int k = 0; k < CC; ++k) {
    float v = rlf(fin, k);
    bool g = v > bv;
    bv = g ? v : bv;
    bt = g ? k : bt;
  }
  if (lane == 0) { meta[b] = n; meta[BB + b] = bt; }
}

// ---------------- parallel replay: backpointers from exact checkpoints ----------------
__global__ __launch_bounds__(64) void k_rep(const float* __restrict__ emit,
                                            const float* __restrict__ trans,
                                            const float* __restrict__ pv,
                                            const int* __restrict__ meta,
                                            unsigned char* __restrict__ bp) {
  const int c = blockIdx.x, b = blockIdx.y;
  const int lane = threadIdx.x;
  const int n = meta[b];
  const int t0 = c * CS;
  if (t0 >= n) return;
  const int lc = lane < CC ? lane : CC - 1;
  float Trow[CC];
#pragma unroll
  for (int j = 0; j < CC; ++j) Trow[j] = trans[lc * CC + j];
  float st = pv[((size_t)b * NCH + c) * CC + lc];
  const float* eb = emit + (size_t)b * LL * CC;
  float ev[CS];
#pragma unroll
  for (int q = 0; q < CS; ++q) {
    ev[q] = eb[(t0 + q) * CC + lc];
    asm volatile("" : "+v"(ev[q]));
  }
  unsigned char* bpb = bp + (size_t)b * LL * CC;
  const int m = (n - t0) < CS ? (n - t0) : CS;
#pragma unroll
  for (int q = 0; q < CS; ++q) {
    if (q < m) {
      float cand[CC];
#pragma unroll
      for (int j = 0; j < CC; ++j) cand[j] = rlf(st, j) + Trow[j];
      float m0 = fmaxf(fmaxf(cand[0], cand[1]), cand[2]);
      float m1 = fmaxf(fmaxf(cand[3], cand[4]), cand[5]);
      float m2 = fmaxf(fmaxf(cand[6], cand[7]), cand[8]);
      float m3 = fmaxf(fmaxf(cand[9], cand[10]), cand[11]);
      float m4 = fmaxf(fmaxf(cand[12], cand[13]), cand[14]);
      float m5 = fmaxf(fmaxf(cand[15], cand[16]), cand[17]);
      float m6 = fmaxf(fmaxf(cand[18], cand[19]), cand[20]);
      float n0 = fmaxf(fmaxf(m0, m1), m2);
      float n1 = fmaxf(fmaxf(m3, m4), m5);
      float n2 = fmaxf(m6, cand[21]);
      float mx = fmaxf(fmaxf(n0, n1), n2);
      // first-index argmax over frm (matches jnp.argmax tie-break)
      unsigned u = 0;
#pragma unroll
      for (int j = 0; j < CC; ++j) u |= (cand[j] == mx) ? (1u << j) : 0u;
      int bpi = __builtin_ctz(u);
      if (lane < CC) bpb[(t0 + q) * CC + lane] = (unsigned char)bpi;
      st = mx + ev[q];
    }
  }
}

// ---------------- backtrace: chunk-composed backpointer maps ----------------
__global__ __launch_bounds__(64) void k_back(const unsigned char* __restrict__ bp,
                                             const int* __restrict__ meta,
                                             float* __restrict__ out_path) {
  __shared__ __align__(16) unsigned char bps[LL * CC];  // 11264 B
  __shared__ unsigned char gs[64 * CC];                 // per-chunk composed maps
  const int b = blockIdx.x, lane = threadIdx.x;
  const int n = meta[b];
  const int bt = meta[BB + b];
  const uint32_t* src = (const uint32_t*)(bp + (size_t)b * LL * CC);
  uint32_t* dst = (uint32_t*)bps;
  for (int i = lane; i < (LL * CC) / 4; i += 64) dst[i] = src[i];
  __syncthreads();
  // lane k composes the 8-step map of chunk k (inactive steps = identity)
  const int k = lane;
  for (int c = 0; c < CC; ++c) {
    int tag = c;
#pragma unroll
    for (int j = 7; j >= 0; --j) {
      int t = 8 * k + j;
      int nv = bps[t * CC + tag];
      tag = (t < n) ? nv : tag;
    }
    gs[k * CC + c] = (unsigned char)tag;
  }
  __syncthreads();
  // 64-step dependent chain over chunk maps (broadcast LDS reads)
  int tag = bt, entry = bt;
  for (int kk = 63; kk >= 0; --kk) {
    if (lane == kk) entry = tag;
    tag = gs[kk * CC + tag];
  }
  // parallel replay within each chunk
  tag = entry;
  float* op = out_path + (size_t)b * LL;
#pragma unroll
  for (int j = 7; j >= 0; --j) {
    int t = 8 * k + j;
    bool act = t < n;
    op[t] = act ? (float)tag : 0.0f;
    int nv = bps[t * CC + tag];
    tag = act ? nv : tag;
  }
}

extern "C" void kernel_launch(void* const* d_in, const int* in_sizes, int n_in,
                              void* d_out, int out_size, void* d_ws, size_t ws_size,
                              hipStream_t stream) {
  const float* x = (const float*)d_in[0];
  const float* mask = (const float*)d_in[1];
  const float* W = (const float*)d_in[2];
  const float* bias = (const float*)d_in[3];
  const float* trans = (const float*)d_in[4];
  float* out_score = (float*)d_out;                 // [B, C] f32
  float* out_path = (float*)d_out + BB * CC;        // [B, L] written as f32 values
  char* ws = (char*)d_ws;
  float* emit = (float*)ws;
  unsigned char* bp = (unsigned char*)(ws + BP_OFF);
  int* meta = (int*)(ws + META_OFF);
  float* pvp = (float*)(ws + PV_OFF);

  k_emit<<<dim3(1408), dim3(256), 0, stream>>>(x, W, bias, emit);
  k_pfx<<<dim3(BB), dim3(64), 0, stream>>>(emit, mask, trans, out_score, pvp, meta);
  k_rep<<<dim3(NCH, BB), dim3(64), 0, stream>>>(emit, trans, pvp, meta, bp);
  k_back<<<dim3(BB), dim3(64), 0, stream>>>(bp, meta, out_path);
}